// Round 1
// baseline (373.834 us; speedup 1.0000x reference)
//
#include <hip/hip_runtime.h>

// Problem constants (fixed by the benchmark): z_e [32,64,64,64] f32, emb [1024,64] f32.
constexpr int Cdim = 64;      // channel dim
constexpr int Kcb  = 1024;    // codebook size
constexpr int HWs  = 64 * 64; // 4096 spatial per batch
constexpr int Npts = 32 * HWs; // 131072 points

// One thread per point. All lanes iterate the same code k in lockstep ->
// embedding row loads are wave-uniform (s_load + SGPR operand into v_fma).
__global__ __launch_bounds__(256) void vq_argmin_gather_kernel(
    const float* __restrict__ ze,
    const float* __restrict__ emb,
    float* __restrict__ out) {
  __shared__ float en_s[Kcb];

  const int t = threadIdx.x;

  // --- per-block e-norm table (trivial cost: 64KB read, 256 fma/thread) ---
  #pragma unroll
  for (int r = 0; r < 4; ++r) {
    const int k = t + r * 256;
    const float4* row = reinterpret_cast<const float4*>(emb + (k << 6));
    float a0 = 0.f, a1 = 0.f, a2 = 0.f, a3 = 0.f;
    #pragma unroll
    for (int j = 0; j < 16; ++j) {
      float4 v = row[j];
      a0 = fmaf(v.x, v.x, a0);
      a1 = fmaf(v.y, v.y, a1);
      a2 = fmaf(v.z, v.z, a2);
      a3 = fmaf(v.w, v.w, a3);
    }
    en_s[k] = (a0 + a1) + (a2 + a3);
  }
  __syncthreads();

  // --- load this thread's point vector x (strided by HW in c, coalesced across lanes) ---
  const int n  = blockIdx.x * 256 + t;
  const int b  = n >> 12;          // n / 4096
  const int hw = n & (HWs - 1);
  const float* xp = ze + (b * Cdim) * HWs + hw;
  float x[Cdim];
  #pragma unroll
  for (int c = 0; c < Cdim; ++c) x[c] = xp[c * HWs];

  float xn0 = 0.f, xn1 = 0.f, xn2 = 0.f, xn3 = 0.f;
  #pragma unroll
  for (int c = 0; c < Cdim; c += 4) {
    xn0 = fmaf(x[c + 0], x[c + 0], xn0);
    xn1 = fmaf(x[c + 1], x[c + 1], xn1);
    xn2 = fmaf(x[c + 2], x[c + 2], xn2);
    xn3 = fmaf(x[c + 3], x[c + 3], xn3);
  }
  const float xnorm = (xn0 + xn1) + (xn2 + xn3);

  // --- scan all K codes; k is wave-uniform each iteration ---
  float best  = 3.4e38f;
  int   bestk = 0;
  #pragma unroll 2
  for (int k = 0; k < Kcb; ++k) {
    const float4* er = reinterpret_cast<const float4*>(emb + (k << 6));
    float d0 = 0.f, d1 = 0.f, d2 = 0.f, d3 = 0.f;
    #pragma unroll
    for (int j = 0; j < 16; ++j) {
      float4 v = er[j];
      d0 = fmaf(x[4 * j + 0], v.x, d0);
      d1 = fmaf(x[4 * j + 1], v.y, d1);
      d2 = fmaf(x[4 * j + 2], v.z, d2);
      d3 = fmaf(x[4 * j + 3], v.w, d3);
    }
    const float dot = (d0 + d1) + (d2 + d3);
    const float tt  = xnorm + en_s[k];
    // match numpy: t - 2*dot with explicit mul+sub rounding (no fma contraction)
    const float d = __fsub_rn(tt, __fmul_rn(2.0f, dot));
    if (d < best) { best = d; bestk = k; }  // strict < keeps first index on ties
  }

  // --- gather winning embedding row; out[c*N + n] = E[bestk][c] ---
  const float4* brow = reinterpret_cast<const float4*>(emb + (bestk << 6));
  #pragma unroll
  for (int j = 0; j < 16; ++j) {
    float4 v = brow[j];
    out[(4 * j + 0) * Npts + n] = v.x;
    out[(4 * j + 1) * Npts + n] = v.y;
    out[(4 * j + 2) * Npts + n] = v.z;
    out[(4 * j + 3) * Npts + n] = v.w;
  }
}

extern "C" void kernel_launch(void* const* d_in, const int* in_sizes, int n_in,
                              void* d_out, int out_size, void* d_ws, size_t ws_size,
                              hipStream_t stream) {
  (void)in_sizes; (void)n_in; (void)d_ws; (void)ws_size; (void)out_size;
  const float* ze  = (const float*)d_in[0];
  const float* emb = (const float*)d_in[1];
  float* out = (float*)d_out;

  vq_argmin_gather_kernel<<<Npts / 256, 256, 0, stream>>>(ze, emb, out);
}